// Round 12
// baseline (319.983 us; speedup 1.0000x reference)
//
#include <hip/hip_runtime.h>
#include <hip/hip_bf16.h>
#include <math.h>

#define DIN 500
#define DHID 128
#define DOUT 40
#define ZS 48   // z-row stride (bf16): 96B = always exactly 2 cache lines; z = 4.8MB (~L2)

typedef __attribute__((ext_vector_type(8))) short bf16x8;
typedef __attribute__((ext_vector_type(4))) float f32x4;

__device__ inline short f2bf(float f) {
    __hip_bfloat16 b = __float2bfloat16(f);
    return *reinterpret_cast<short*>(&b);
}
__device__ inline float bflo(unsigned u) {
    unsigned v = u << 16;
    return __builtin_bit_cast(float, v);
}
__device__ inline float bfhi(unsigned u) {
    unsigned v = u & 0xffff0000u;
    return __builtin_bit_cast(float, v);
}
__device__ inline unsigned packbf(float a, float b) {
    unsigned lo = (unsigned)(unsigned short)f2bf(a);
    unsigned hi = (unsigned)(unsigned short)f2bf(b);
    return lo | (hi << 16);
}

// ---------------- K1: zero cnt + M2 = W2 @ W3 ----------------
__global__ __launch_bounds__(256) void k_init(
    int* __restrict__ cnt, int nzero,
    const float* __restrict__ W2, const float* __restrict__ W3,
    float* __restrict__ M2) {
    int gtid = blockIdx.x * 256 + threadIdx.x;
    int gsz = gridDim.x * 256;
    for (int i = gtid; i < nzero; i += gsz) cnt[i] = 0;
    for (int idx = gtid; idx < 128 * 40; idx += gsz) {
        int a = idx / 40, j = idx % 40;
        float s = 0.f;
        #pragma unroll 8
        for (int b = 0; b < 128; ++b) s += W2[a * 128 + b] * W3[b * 40 + j];
        M2[idx] = s;
    }
}

// ---------------- K2: in-degree count + per-edge rank (atomic's return) ----------------
__global__ void k_count(const int* __restrict__ col, int* __restrict__ cnt,
                        int* __restrict__ posw, int E) {
    int e = blockIdx.x * blockDim.x + threadIdx.x;
    if (e < E) posw[e] = atomicAdd(&cnt[col[e]], 1);
}

// ---------------- K3: dinv + per-chunk scan + WT + cvec + off[N]=E ----------------
__global__ __launch_bounds__(256) void k_prep(
    const int* __restrict__ cnt, float* __restrict__ dinv,
    int* __restrict__ off, int* __restrict__ bsum,
    const float* __restrict__ W1, const float* __restrict__ M2,
    const float* __restrict__ b1, const float* __restrict__ b2,
    const float* __restrict__ W3,
    __hip_bfloat16* __restrict__ WT, float* __restrict__ c1, float* __restrict__ c2,
    int N, int E, int nb) {
    __shared__ int part[256];
    const int tid = threadIdx.x;
    const int gtid = blockIdx.x * 256 + tid;
    const int gsz = gridDim.x * 256;

    if ((int)blockIdx.x < nb) {
        int base = blockIdx.x * 1024 + tid * 4;
        int4 v = {0, 0, 0, 0};
        if (base + 3 < N) v = *(const int4*)(cnt + base);
        else {
            if (base + 0 < N) v.x = cnt[base + 0];
            if (base + 1 < N) v.y = cnt[base + 1];
            if (base + 2 < N) v.z = cnt[base + 2];
            if (base + 3 < N) v.w = cnt[base + 3];
        }
        int s = v.x + v.y + v.z + v.w;
        part[tid] = s;
        __syncthreads();
        for (int d = 1; d < 256; d <<= 1) {
            int u = (tid >= d) ? part[tid - d] : 0;
            __syncthreads();
            part[tid] += u;
            __syncthreads();
        }
        int ex = part[tid] - s;
        if (base + 0 < N) off[base + 0] = ex;
        if (base + 1 < N) off[base + 1] = ex + v.x;
        if (base + 2 < N) off[base + 2] = ex + v.x + v.y;
        if (base + 3 < N) off[base + 3] = ex + v.x + v.y + v.z;
        if (tid == 255) bsum[blockIdx.x] = part[255];
    }
    for (int i = gtid; i < N; i += gsz) dinv[i] = rsqrtf((float)cnt[i] + 1.0f);
    for (int idx = gtid; idx < 64 * 512; idx += gsz) {
        int nn = idx >> 9, k = idx & 511;
        float s = 0.f;
        if (nn < 40 && k < 500) {
            #pragma unroll 8
            for (int a = 0; a < 128; ++a) s += W1[k * 128 + a] * M2[a * 40 + nn];
        }
        WT[idx] = __float2bfloat16(s);
    }
    for (int j = gtid; j < 40; j += gsz) {
        float s1 = 0.f, s2 = 0.f;
        #pragma unroll 8
        for (int a = 0; a < 128; ++a) {
            s1 += b1[a] * M2[a * 40 + j];
            s2 += b2[a] * W3[a * 40 + j];
        }
        c1[j] = s1;
        c2[j] = s2;
    }
    if (gtid == 0) off[N] = E;
}

// ---------------- K4: add chunk prefixes (redundant per-block bsum scan) ----------------
__global__ __launch_bounds__(256) void k_scan_add(
    int* __restrict__ off, const int* __restrict__ bsum, int N, int nb) {
    __shared__ int sAdd;
    const int tid = threadIdx.x;
    const int blk = blockIdx.x + 1;
    if (tid < 64) {
        int v = (tid < nb) ? bsum[tid] : 0;
        int inc = v;
        #pragma unroll
        for (int d = 1; d < 64; d <<= 1) {
            int u = __shfl_up(inc, d);
            if (tid >= d) inc += u;
        }
        int add = __shfl(inc, blk - 1);
        if (tid == 0) sAdd = add;
    }
    __syncthreads();
    int add = sAdd;
    int base = blk * 1024 + tid * 4;
    if (base + 3 < N) {
        int4 v = *(int4*)(off + base);
        v.x += add; v.y += add; v.z += add; v.w += add;
        *(int4*)(off + base) = v;
    } else {
        if (base + 0 < N) off[base + 0] += add;
        if (base + 1 < N) off[base + 1] += add;
        if (base + 2 < N) off[base + 2] += add;
        if (base + 3 < N) off[base + 3] += add;
    }
}

// ---------------- K5: FUSED gemm (blocks < gemm_blocks) || scatter (rest) ----------------
// Scatter: atomic-free (pos = off[col] + posw[e]); epack store non-temporal (skip RFO).
__global__ __launch_bounds__(256) void k_gemm_scatter(
    const float* __restrict__ Af, const __hip_bfloat16* __restrict__ WT,
    __hip_bfloat16* __restrict__ C, int M,
    const int* __restrict__ row, const int* __restrict__ col,
    const float* __restrict__ dinv, const int* __restrict__ off,
    const int* __restrict__ posw, int2* __restrict__ epack, int E, int gemm_blocks) {
    __shared__ __align__(16) __hip_bfloat16 As[32 * 64];
    __shared__ __align__(16) __hip_bfloat16 Bs[64 * 64];
    if ((int)blockIdx.x >= gemm_blocks) {
        int e = ((int)blockIdx.x - gemm_blocks) * 256 + threadIdx.x;
        if (e < E) {
            int r = row[e], c = col[e];
            int pos = off[c] + posw[e];
            unsigned long long ev =
                (unsigned)r | ((unsigned long long)(unsigned)__float_as_int(dinv[r] * dinv[c]) << 32);
            __builtin_nontemporal_store(ev, (unsigned long long*)&epack[pos]);
        }
        return;
    }
    const int Kp = 512, Kreal = 500, ldA = 500;
    const int tid = threadIdx.x;
    const int lane = tid & 63, wave = tid >> 6;
    const int wr = wave >> 1, wc = wave & 1;
    const int l15 = lane & 15, quad = lane >> 4;
    const int m0 = blockIdx.x * 32;

    const int sa_row = tid >> 3;
    const int sa_ch  = tid & 7;
    const int sa_gm  = m0 + sa_row;
    const bool sa_ok = sa_gm < M;
    const int aBase  = sa_gm * ldA + sa_ch * 8;
    const int sa_lds = sa_row * 64 + ((sa_ch ^ (sa_row & 7)) << 3);

    int bOff[2], sb_lds[2];
    #pragma unroll
    for (int it = 0; it < 2; ++it) {
        int cid = tid + it * 256;
        int r = cid >> 3, ch = cid & 7;
        bOff[it] = r * Kp + ch * 8;
        sb_lds[it] = r * 64 + ((ch ^ (r & 7)) << 3);
    }

    f32x4 acc[2] = {};
    float4 pa0, pa1;
    bf16x8 pb[2];
    pa0 = pa1 = float4{0, 0, 0, 0};
    { bf16x8 z = {}; pb[0] = pb[1] = z; }

    auto load_tile = [&](int k0) {
        int k = k0 + sa_ch * 8;
        if (sa_ok && k + 8 <= Kreal) {
            pa0 = *(const float4*)(Af + aBase + k0);
            pa1 = *(const float4*)(Af + aBase + k0 + 4);
        } else {
            float v[8];
            #pragma unroll
            for (int u = 0; u < 8; ++u)
                v[u] = (sa_ok && k + u < Kreal) ? Af[aBase + k0 + u] : 0.0f;
            pa0 = float4{v[0], v[1], v[2], v[3]};
            pa1 = float4{v[4], v[5], v[6], v[7]};
        }
        #pragma unroll
        for (int it = 0; it < 2; ++it)
            pb[it] = *(const bf16x8*)(WT + bOff[it] + k0);
    };

    auto write_tile = [&]() {
        bf16x8 av;
        av[0] = f2bf(pa0.x); av[1] = f2bf(pa0.y);
        av[2] = f2bf(pa0.z); av[3] = f2bf(pa0.w);
        av[4] = f2bf(pa1.x); av[5] = f2bf(pa1.y);
        av[6] = f2bf(pa1.z); av[7] = f2bf(pa1.w);
        *(bf16x8*)&As[sa_lds] = av;
        #pragma unroll
        for (int it = 0; it < 2; ++it)
            *(bf16x8*)&Bs[sb_lds[it]] = pb[it];
    };

    load_tile(0);
    write_tile();
    __syncthreads();

    const int nt = Kp >> 6;  // 8
    for (int t = 0; t < nt; ++t) {
        if (t + 1 < nt) load_tile((t + 1) << 6);
        #pragma unroll
        for (int s = 0; s < 2; ++s) {
            const int chs = ((s * 4 + quad) ^ (l15 & 7)) << 3;
            bf16x8 a0 = *(const bf16x8*)&As[(wr * 16 + l15) * 64 + chs];
            bf16x8 b0 = *(const bf16x8*)&Bs[(wc * 32 + l15) * 64 + chs];
            bf16x8 b1 = *(const bf16x8*)&Bs[(wc * 32 + 16 + l15) * 64 + chs];
            acc[0] = __builtin_amdgcn_mfma_f32_16x16x32_bf16(a0, b0, acc[0], 0, 0, 0);
            acc[1] = __builtin_amdgcn_mfma_f32_16x16x32_bf16(a0, b1, acc[1], 0, 0, 0);
        }
        __syncthreads();
        if (t + 1 < nt) { write_tile(); __syncthreads(); }
    }

    // store only live cols (< ZS); cols 40-47 are zeros from zero-padded WT
    #pragma unroll
    for (int r = 0; r < 4; ++r) {
        int gm = m0 + wr * 16 + quad * 4 + r;
        if (gm >= M) continue;
        #pragma unroll
        for (int j = 0; j < 2; ++j) {
            int gn = wc * 32 + j * 16 + l15;
            if (gn < ZS) C[(long)gm * ZS + gn] = __float2bfloat16(acc[j][r]);
        }
    }
}

// ---------------- K6-8: propagation zout = Ahat @ zin (48-wide bf16 rows, 96B) ----------------
// Quarter-wave edge groups; lanes l16<12 cover the 48 cols (uint2 each); lanes 12-15 are
// dead (loads spill harmlessly into the padded next row, never written). Invalid edge
// slots redirect to own row (L1-hot). s-scalar rides cols 40-41 (bit-exact f32).
template <int MODE>
__global__ __launch_bounds__(256) void prop64_kernel(
    const __hip_bfloat16* __restrict__ zin, const float* __restrict__ dinv,
    const int* __restrict__ off, const int2* __restrict__ epack,
    float* __restrict__ sout,
    const float* __restrict__ s1v, const float* __restrict__ s2v,
    const float* __restrict__ c1, const float* __restrict__ c2,
    const float* __restrict__ b3,
    __hip_bfloat16* __restrict__ zout, float* __restrict__ out, int n) {
    int wid = (blockIdx.x * blockDim.x + threadIdx.x) >> 6;
    int lane = threadIdx.x & 63;
    if (wid >= n) return;
    const int q = lane >> 4, l16 = lane & 15;
    const int c = l16 * 4;          // 4 bf16 cols per lane; live iff c < ZS (l16 < 12)
    const bool lv = (l16 < 12);
    const bool sl = (l16 == 10);    // s-lane: u.x spans cols 40-41 = embedded f32
    float a0 = 0.f, a1 = 0.f, a2 = 0.f, a3 = 0.f, sacc = 0.f;
    float di = dinv[wid];
    float dsq = di * di;
    if (q == 0) {  // self-loop term once (quarter 0)
        uint2 su = *(const uint2*)(zin + (long)wid * ZS + c);
        a0 = dsq * bflo(su.x);
        a1 = dsq * bfhi(su.x);
        a2 = dsq * bflo(su.y);
        a3 = dsq * bfhi(su.y);
        if (MODE == 0) sacc = dsq;
        if (MODE == 1) sacc = sl ? dsq * __builtin_bit_cast(float, su.x) : 0.0f;
    }
    const int pe = off[wid + 1];
    for (int p = off[wid] + q; p < pe; p += 16) {
        #pragma unroll
        for (int j = 0; j < 4; ++j) {
            int pj = p + 4 * j;
            bool ok = (pj < pe);
            int pc = ok ? pj : (pe - 1);
            int2 ev = epack[pc];
            float w = ok ? __int_as_float(ev.y) : 0.0f;
            int src = ok ? ev.x : wid;               // invalid slot -> own row (L1-hot)
            uint2 u = *(const uint2*)(zin + (long)src * ZS + c);
            a0 += w * bflo(u.x);
            a1 += w * bfhi(u.x);
            a2 += w * bflo(u.y);
            a3 += w * bfhi(u.y);
            if (MODE == 0) sacc += w;
            if (MODE == 1) sacc += sl ? w * __builtin_bit_cast(float, u.x) : 0.0f;
        }
    }
    a0 += __shfl_xor(a0, 16); a0 += __shfl_xor(a0, 32);
    a1 += __shfl_xor(a1, 16); a1 += __shfl_xor(a1, 32);
    a2 += __shfl_xor(a2, 16); a2 += __shfl_xor(a2, 32);
    a3 += __shfl_xor(a3, 16); a3 += __shfl_xor(a3, 32);
    if (MODE < 2) {
        sacc += __shfl_xor(sacc, 16); sacc += __shfl_xor(sacc, 32);
        if (q == 0 && lv) {
            uint2 ov;
            if (sl) {  // embed the new scalar bit-exactly in cols 40-41; cols 42-43 = 0
                ov.x = __builtin_bit_cast(unsigned, sacc);
                ov.y = 0;
                sout[wid] = sacc;
            } else {
                ov.x = packbf(a0, a1);
                ov.y = packbf(a2, a3);
            }
            *(uint2*)(zout + (long)wid * ZS + c) = ov;
        }
    } else {
        float s1 = s1v[wid], s2 = s2v[wid];
        float4 cv1 = {0, 0, 0, 0}, cv2 = {0, 0, 0, 0}, bv = {0, 0, 0, 0};
        const bool live = (c < DOUT);
        if (live) {
            cv1 = *(const float4*)(c1 + c);
            cv2 = *(const float4*)(c2 + c);
            bv  = *(const float4*)(b3 + c);
        }
        float v0 = live ? a0 + s2 * cv1.x + s1 * cv2.x + bv.x : -INFINITY;
        float v1 = live ? a1 + s2 * cv1.y + s1 * cv2.y + bv.y : -INFINITY;
        float v2 = live ? a2 + s2 * cv1.z + s1 * cv2.z + bv.z : -INFINITY;
        float v3 = live ? a3 + s2 * cv1.w + s1 * cv2.w + bv.w : -INFINITY;
        float m = fmaxf(fmaxf(v0, v1), fmaxf(v2, v3));
        #pragma unroll
        for (int o = 8; o; o >>= 1) m = fmaxf(m, __shfl_xor(m, o));
        float ex = live ? (expf(v0 - m) + expf(v1 - m) + expf(v2 - m) + expf(v3 - m)) : 0.0f;
        float sum = ex;
        #pragma unroll
        for (int o = 8; o; o >>= 1) sum += __shfl_xor(sum, o);
        float ls = logf(sum);
        if (q == 0 && live) {
            float4 ov;
            ov.x = v0 - m - ls;
            ov.y = v1 - m - ls;
            ov.z = v2 - m - ls;
            ov.w = v3 - m - ls;
            *(float4*)(out + (long)wid * DOUT + c) = ov;
        }
    }
}

extern "C" void kernel_launch(void* const* d_in, const int* in_sizes, int n_in,
                              void* d_out, int out_size, void* d_ws, size_t ws_size,
                              hipStream_t stream) {
    const float* x  = (const float*)d_in[0];
    const int*   ei = (const int*)d_in[1];
    const float* W1 = (const float*)d_in[2];
    const float* b1 = (const float*)d_in[3];
    const float* W2 = (const float*)d_in[4];
    const float* b2 = (const float*)d_in[5];
    const float* W3 = (const float*)d_in[6];
    const float* b3 = (const float*)d_in[7];
    float* out = (float*)d_out;

    const int N = in_sizes[0] / DIN;  // 50000
    const int E = in_sizes[1] / 2;    // 600000
    const int* row = ei;
    const int* col = ei + E;

    // workspace layout:
    // dinv[Na] | cnt[Na] | off[Na] | bsum[256] | posw[Ea] | epack[Ea] int2 |
    // y[N*ZS+16] bf16 | z1[N*ZS+16] bf16 | s1[Na] | s2[Na] | M2[128*40] | c1[64] | c2[64] | WT
    const int Na = (N + 255) & ~255;
    const int Ea = (E + 255) & ~255;
    float* dinv   = (float*)d_ws;
    int*   cnt    = (int*)(dinv + Na);
    int*   off    = cnt + Na;
    int*   bsum   = off + Na;
    int*   posw   = bsum + 256;
    int2*  epack  = (int2*)(posw + Ea);
    __hip_bfloat16* y  = (__hip_bfloat16*)(epack + Ea);
    __hip_bfloat16* z1 = y + (long)N * ZS + 16;   // +16 elem pad for dead-lane spill reads
    float* s1 = (float*)(z1 + (long)N * ZS + 16);
    float* s2 = s1 + Na;
    float* M2 = s2 + Na;
    float* c1 = M2 + 128 * 40;
    float* c2 = c1 + 64;
    __hip_bfloat16* WT = (__hip_bfloat16*)(c2 + 64);

    const int B = 256;
    const int nb = (N + 1023) / 1024;  // 49
    int gemm_grid = (N + 31) / 32;     // 1563
    int scat_grid = (E + B - 1) / B;   // 2344
    int node_wave_blocks = (int)(((long)N * 64 + B - 1) / B);  // 12500

    // K1: zero cnt, M2 = W2 @ W3
    k_init<<<(Na + B - 1) / B, B, 0, stream>>>(cnt, Na, W2, W3, M2);
    // K2: in-degree count + per-edge rank
    k_count<<<(E + B - 1) / B, B, 0, stream>>>(col, cnt, posw, E);
    // K3: dinv + chunk scan + WT + cvec + off[N]=E
    k_prep<<<256, B, 0, stream>>>(cnt, dinv, off, bsum, W1, M2, b1, b2, W3,
                                  WT, c1, c2, N, E, nb);
    // K4: chunk-prefix add
    k_scan_add<<<nb - 1, B, 0, stream>>>(off, bsum, N, nb);
    // K5: fused gemm || atomic-free scatter (nt epack store)
    k_gemm_scatter<<<gemm_grid + scat_grid, B, 0, stream>>>(
        x, WT, y, N, row, col, dinv, off, posw, epack, E, gemm_grid);
    // K6-8: three Ahat propagations (s embedded in cols 40-41 of z rows)
    prop64_kernel<0><<<node_wave_blocks, B, 0, stream>>>(
        y, dinv, off, epack, s1, nullptr, nullptr, nullptr, nullptr, nullptr,
        z1, nullptr, N);
    prop64_kernel<1><<<node_wave_blocks, B, 0, stream>>>(
        z1, dinv, off, epack, s2, nullptr, nullptr, nullptr, nullptr, nullptr,
        y, nullptr, N);
    prop64_kernel<2><<<node_wave_blocks, B, 0, stream>>>(
        y, dinv, off, epack, nullptr, s1, s2, c1, c2, b3,
        nullptr, out, N);
}

// Round 13
// 315.061 us; speedup vs baseline: 1.0156x; 1.0156x over previous
//
#include <hip/hip_runtime.h>
#include <hip/hip_bf16.h>
#include <math.h>

#define DIN 500
#define DHID 128
#define DOUT 40
#define ZS 64   // z-row stride (bf16): 128B aligned = minimal line count per row

typedef __attribute__((ext_vector_type(8))) short bf16x8;
typedef __attribute__((ext_vector_type(4))) float f32x4;

__device__ inline short f2bf(float f) {
    __hip_bfloat16 b = __float2bfloat16(f);
    return *reinterpret_cast<short*>(&b);
}
__device__ inline float bflo(unsigned u) {
    unsigned v = u << 16;
    return __builtin_bit_cast(float, v);
}
__device__ inline float bfhi(unsigned u) {
    unsigned v = u & 0xffff0000u;
    return __builtin_bit_cast(float, v);
}
__device__ inline unsigned packbf(float a, float b) {
    unsigned lo = (unsigned)(unsigned short)f2bf(a);
    unsigned hi = (unsigned)(unsigned short)f2bf(b);
    return lo | (hi << 16);
}

// ---------------- K1: zero cnt + M2 = W2 @ W3 ----------------
__global__ __launch_bounds__(256) void k_init(
    int* __restrict__ cnt, int nzero,
    const float* __restrict__ W2, const float* __restrict__ W3,
    float* __restrict__ M2) {
    int gtid = blockIdx.x * 256 + threadIdx.x;
    int gsz = gridDim.x * 256;
    for (int i = gtid; i < nzero; i += gsz) cnt[i] = 0;
    for (int idx = gtid; idx < 128 * 40; idx += gsz) {
        int a = idx / 40, j = idx % 40;
        float s = 0.f;
        #pragma unroll 8
        for (int b = 0; b < 128; ++b) s += W2[a * 128 + b] * W3[b * 40 + j];
        M2[idx] = s;
    }
}

// ---------------- K2: FUSED in-degree count+rank (blocks < cblocks) || WT || cvec ----------------
// WT/cvec depend only on M2 (k_init) -> overlap them with the atomic storm.
__global__ __launch_bounds__(256) void k_count(
    const int* __restrict__ col, int* __restrict__ cnt, int* __restrict__ posw, int E,
    const float* __restrict__ W1, const float* __restrict__ M2,
    const float* __restrict__ b1, const float* __restrict__ b2,
    const float* __restrict__ W3,
    __hip_bfloat16* __restrict__ WT, float* __restrict__ c1, float* __restrict__ c2,
    int cblocks) {
    const int b = blockIdx.x;
    const int tid = threadIdx.x;
    if (b < cblocks) {
        int e = b * 256 + tid;
        if (e < E) posw[e] = atomicAdd(&cnt[col[e]], 1);
        return;
    }
    int wb = b - cblocks;
    if (wb < 128) {  // WT[n][k] = bf16((W1 @ M2)^T), 64 x 512 zero-padded
        int idx = wb * 256 + tid;  // 0..32767
        int nn = idx >> 9, k = idx & 511;
        float s = 0.f;
        if (nn < 40 && k < 500) {
            #pragma unroll 8
            for (int a = 0; a < 128; ++a) s += W1[k * 128 + a] * M2[a * 40 + nn];
        }
        WT[idx] = __float2bfloat16(s);
        return;
    }
    // cvec block: c1 = b1 @ M2, c2 = b2 @ W3
    if (tid < 40) {
        float s1 = 0.f, s2 = 0.f;
        #pragma unroll 8
        for (int a = 0; a < 128; ++a) {
            s1 += b1[a] * M2[a * 40 + tid];
            s2 += b2[a] * W3[a * 40 + tid];
        }
        c1[tid] = s1;
        c2[tid] = s2;
    }
}

// ---------------- K3: dinv + per-chunk scan + off[N]=E ----------------
__global__ __launch_bounds__(256) void k_prep(
    const int* __restrict__ cnt, float* __restrict__ dinv,
    int* __restrict__ off, int* __restrict__ bsum,
    int N, int E, int nb) {
    __shared__ int part[256];
    const int tid = threadIdx.x;
    const int gtid = blockIdx.x * 256 + tid;
    const int gsz = gridDim.x * 256;

    if ((int)blockIdx.x < nb) {
        int base = blockIdx.x * 1024 + tid * 4;
        int4 v = {0, 0, 0, 0};
        if (base + 3 < N) v = *(const int4*)(cnt + base);
        else {
            if (base + 0 < N) v.x = cnt[base + 0];
            if (base + 1 < N) v.y = cnt[base + 1];
            if (base + 2 < N) v.z = cnt[base + 2];
            if (base + 3 < N) v.w = cnt[base + 3];
        }
        int s = v.x + v.y + v.z + v.w;
        part[tid] = s;
        __syncthreads();
        for (int d = 1; d < 256; d <<= 1) {
            int u = (tid >= d) ? part[tid - d] : 0;
            __syncthreads();
            part[tid] += u;
            __syncthreads();
        }
        int ex = part[tid] - s;
        if (base + 0 < N) off[base + 0] = ex;
        if (base + 1 < N) off[base + 1] = ex + v.x;
        if (base + 2 < N) off[base + 2] = ex + v.x + v.y;
        if (base + 3 < N) off[base + 3] = ex + v.x + v.y + v.z;
        if (tid == 255) bsum[blockIdx.x] = part[255];
    }
    for (int i = gtid; i < N; i += gsz) dinv[i] = rsqrtf((float)cnt[i] + 1.0f);
    if (gtid == 0) off[N] = E;
}

// ---------------- K4: add chunk prefixes (redundant per-block bsum scan) ----------------
__global__ __launch_bounds__(256) void k_scan_add(
    int* __restrict__ off, const int* __restrict__ bsum, int N, int nb) {
    __shared__ int sAdd;
    const int tid = threadIdx.x;
    const int blk = blockIdx.x + 1;
    if (tid < 64) {
        int v = (tid < nb) ? bsum[tid] : 0;
        int inc = v;
        #pragma unroll
        for (int d = 1; d < 64; d <<= 1) {
            int u = __shfl_up(inc, d);
            if (tid >= d) inc += u;
        }
        int add = __shfl(inc, blk - 1);
        if (tid == 0) sAdd = add;
    }
    __syncthreads();
    int add = sAdd;
    int base = blk * 1024 + tid * 4;
    if (base + 3 < N) {
        int4 v = *(int4*)(off + base);
        v.x += add; v.y += add; v.z += add; v.w += add;
        *(int4*)(off + base) = v;
    } else {
        if (base + 0 < N) off[base + 0] += add;
        if (base + 1 < N) off[base + 1] += add;
        if (base + 2 < N) off[base + 2] += add;
        if (base + 3 < N) off[base + 3] += add;
    }
}

// ---------------- K5: FUSED gemm (blocks < gemm_blocks) || scatter (rest) ----------------
// Scatter: atomic-free (pos = off[col] + posw[e]); epack store non-temporal.
__global__ __launch_bounds__(256) void k_gemm_scatter(
    const float* __restrict__ Af, const __hip_bfloat16* __restrict__ WT,
    __hip_bfloat16* __restrict__ C, int M,
    const int* __restrict__ row, const int* __restrict__ col,
    const float* __restrict__ dinv, const int* __restrict__ off,
    const int* __restrict__ posw, int2* __restrict__ epack, int E, int gemm_blocks) {
    __shared__ __align__(16) __hip_bfloat16 As[32 * 64];
    __shared__ __align__(16) __hip_bfloat16 Bs[64 * 64];
    if ((int)blockIdx.x >= gemm_blocks) {
        int e = ((int)blockIdx.x - gemm_blocks) * 256 + threadIdx.x;
        if (e < E) {
            int r = row[e], c = col[e];
            int pos = off[c] + posw[e];
            unsigned long long ev =
                (unsigned)r | ((unsigned long long)(unsigned)__float_as_int(dinv[r] * dinv[c]) << 32);
            __builtin_nontemporal_store(ev, (unsigned long long*)&epack[pos]);
        }
        return;
    }
    const int Kp = 512, Kreal = 500, ldA = 500;
    const int tid = threadIdx.x;
    const int lane = tid & 63, wave = tid >> 6;
    const int wr = wave >> 1, wc = wave & 1;
    const int l15 = lane & 15, quad = lane >> 4;
    const int m0 = blockIdx.x * 32;

    const int sa_row = tid >> 3;
    const int sa_ch  = tid & 7;
    const int sa_gm  = m0 + sa_row;
    const bool sa_ok = sa_gm < M;
    const int aBase  = sa_gm * ldA + sa_ch * 8;
    const int sa_lds = sa_row * 64 + ((sa_ch ^ (sa_row & 7)) << 3);

    int bOff[2], sb_lds[2];
    #pragma unroll
    for (int it = 0; it < 2; ++it) {
        int cid = tid + it * 256;
        int r = cid >> 3, ch = cid & 7;
        bOff[it] = r * Kp + ch * 8;
        sb_lds[it] = r * 64 + ((ch ^ (r & 7)) << 3);
    }

    f32x4 acc[2] = {};
    float4 pa0, pa1;
    bf16x8 pb[2];
    pa0 = pa1 = float4{0, 0, 0, 0};
    { bf16x8 z = {}; pb[0] = pb[1] = z; }

    auto load_tile = [&](int k0) {
        int k = k0 + sa_ch * 8;
        if (sa_ok && k + 8 <= Kreal) {
            pa0 = *(const float4*)(Af + aBase + k0);
            pa1 = *(const float4*)(Af + aBase + k0 + 4);
        } else {
            float v[8];
            #pragma unroll
            for (int u = 0; u < 8; ++u)
                v[u] = (sa_ok && k + u < Kreal) ? Af[aBase + k0 + u] : 0.0f;
            pa0 = float4{v[0], v[1], v[2], v[3]};
            pa1 = float4{v[4], v[5], v[6], v[7]};
        }
        #pragma unroll
        for (int it = 0; it < 2; ++it)
            pb[it] = *(const bf16x8*)(WT + bOff[it] + k0);
    };

    auto write_tile = [&]() {
        bf16x8 av;
        av[0] = f2bf(pa0.x); av[1] = f2bf(pa0.y);
        av[2] = f2bf(pa0.z); av[3] = f2bf(pa0.w);
        av[4] = f2bf(pa1.x); av[5] = f2bf(pa1.y);
        av[6] = f2bf(pa1.z); av[7] = f2bf(pa1.w);
        *(bf16x8*)&As[sa_lds] = av;
        #pragma unroll
        for (int it = 0; it < 2; ++it)
            *(bf16x8*)&Bs[sb_lds[it]] = pb[it];
    };

    load_tile(0);
    write_tile();
    __syncthreads();

    const int nt = Kp >> 6;  // 8
    for (int t = 0; t < nt; ++t) {
        if (t + 1 < nt) load_tile((t + 1) << 6);
        #pragma unroll
        for (int s = 0; s < 2; ++s) {
            const int chs = ((s * 4 + quad) ^ (l15 & 7)) << 3;
            bf16x8 a0 = *(const bf16x8*)&As[(wr * 16 + l15) * 64 + chs];
            bf16x8 b0 = *(const bf16x8*)&Bs[(wc * 32 + l15) * 64 + chs];
            bf16x8 b1 = *(const bf16x8*)&Bs[(wc * 32 + 16 + l15) * 64 + chs];
            acc[0] = __builtin_amdgcn_mfma_f32_16x16x32_bf16(a0, b0, acc[0], 0, 0, 0);
            acc[1] = __builtin_amdgcn_mfma_f32_16x16x32_bf16(a0, b1, acc[1], 0, 0, 0);
        }
        __syncthreads();
        if (t + 1 < nt) { write_tile(); __syncthreads(); }
    }

    #pragma unroll
    for (int r = 0; r < 4; ++r) {
        int gm = m0 + wr * 16 + quad * 4 + r;
        if (gm >= M) continue;
        #pragma unroll
        for (int j = 0; j < 2; ++j) {
            int gn = wc * 32 + j * 16 + l15;
            C[(long)gm * ZS + gn] = __float2bfloat16(acc[j][r]);
        }
    }
}

// ---------------- K6-8: propagation zout = Ahat @ zin (64-wide bf16 rows) ----------------
// Quarter-wave edge groups; predicated rounds; invalid slots redirect to the node's
// OWN row (L1-hot). s-scalar rides cols 40-41 (bit-exact f32) so MODE 1 needs no
// second random load.
template <int MODE>
__global__ __launch_bounds__(256) void prop64_kernel(
    const __hip_bfloat16* __restrict__ zin, const float* __restrict__ dinv,
    const int* __restrict__ off, const int2* __restrict__ epack,
    float* __restrict__ sout,
    const float* __restrict__ s1v, const float* __restrict__ s2v,
    const float* __restrict__ c1, const float* __restrict__ c2,
    const float* __restrict__ b3,
    __hip_bfloat16* __restrict__ zout, float* __restrict__ out, int n) {
    int wid = (blockIdx.x * blockDim.x + threadIdx.x) >> 6;
    int lane = threadIdx.x & 63;
    if (wid >= n) return;
    const int q = lane >> 4, l16 = lane & 15;
    const int c = l16 * 4;          // 4 bf16 cols per lane (uint2)
    const bool sl = (l16 == 10);    // s-lane: its u.x spans cols 40-41 = embedded f32
    float a0 = 0.f, a1 = 0.f, a2 = 0.f, a3 = 0.f, sacc = 0.f;
    float di = dinv[wid];
    float dsq = di * di;
    if (q == 0) {  // self-loop term once (quarter 0)
        uint2 su = *(const uint2*)(zin + (long)wid * ZS + c);
        a0 = dsq * bflo(su.x);
        a1 = dsq * bfhi(su.x);
        a2 = dsq * bflo(su.y);
        a3 = dsq * bfhi(su.y);
        if (MODE == 0) sacc = dsq;
        if (MODE == 1) sacc = sl ? dsq * __builtin_bit_cast(float, su.x) : 0.0f;
    }
    const int pe = off[wid + 1];
    for (int p = off[wid] + q; p < pe; p += 16) {
        #pragma unroll
        for (int j = 0; j < 4; ++j) {
            int pj = p + 4 * j;
            bool ok = (pj < pe);
            int pc = ok ? pj : (pe - 1);
            int2 ev = epack[pc];
            float w = ok ? __int_as_float(ev.y) : 0.0f;
            int src = ok ? ev.x : wid;               // invalid slot -> own row (L1-hot)
            uint2 u = *(const uint2*)(zin + (long)src * ZS + c);
            a0 += w * bflo(u.x);
            a1 += w * bfhi(u.x);
            a2 += w * bflo(u.y);
            a3 += w * bfhi(u.y);
            if (MODE == 0) sacc += w;
            if (MODE == 1) sacc += sl ? w * __builtin_bit_cast(float, u.x) : 0.0f;
        }
    }
    a0 += __shfl_xor(a0, 16); a0 += __shfl_xor(a0, 32);
    a1 += __shfl_xor(a1, 16); a1 += __shfl_xor(a1, 32);
    a2 += __shfl_xor(a2, 16); a2 += __shfl_xor(a2, 32);
    a3 += __shfl_xor(a3, 16); a3 += __shfl_xor(a3, 32);
    if (MODE < 2) {
        sacc += __shfl_xor(sacc, 16); sacc += __shfl_xor(sacc, 32);
        if (q == 0) {
            uint2 ov;
            if (sl) {  // embed the new scalar bit-exactly in cols 40-41; cols 42-43 = 0
                ov.x = __builtin_bit_cast(unsigned, sacc);
                ov.y = 0;
                sout[wid] = sacc;
            } else {
                ov.x = packbf(a0, a1);
                ov.y = packbf(a2, a3);
            }
            *(uint2*)(zout + (long)wid * ZS + c) = ov;
        }
    } else {
        float s1 = s1v[wid], s2 = s2v[wid];
        float4 cv1 = {0, 0, 0, 0}, cv2 = {0, 0, 0, 0}, bv = {0, 0, 0, 0};
        const bool live = (c < DOUT);
        if (live) {
            cv1 = *(const float4*)(c1 + c);
            cv2 = *(const float4*)(c2 + c);
            bv  = *(const float4*)(b3 + c);
        }
        float v0 = live ? a0 + s2 * cv1.x + s1 * cv2.x + bv.x : -INFINITY;
        float v1 = live ? a1 + s2 * cv1.y + s1 * cv2.y + bv.y : -INFINITY;
        float v2 = live ? a2 + s2 * cv1.z + s1 * cv2.z + bv.z : -INFINITY;
        float v3 = live ? a3 + s2 * cv1.w + s1 * cv2.w + bv.w : -INFINITY;
        float m = fmaxf(fmaxf(v0, v1), fmaxf(v2, v3));
        #pragma unroll
        for (int o = 8; o; o >>= 1) m = fmaxf(m, __shfl_xor(m, o));
        float ex = live ? (expf(v0 - m) + expf(v1 - m) + expf(v2 - m) + expf(v3 - m)) : 0.0f;
        float sum = ex;
        #pragma unroll
        for (int o = 8; o; o >>= 1) sum += __shfl_xor(sum, o);
        float ls = logf(sum);
        if (q == 0 && live) {
            float4 ov;
            ov.x = v0 - m - ls;
            ov.y = v1 - m - ls;
            ov.z = v2 - m - ls;
            ov.w = v3 - m - ls;
            *(float4*)(out + (long)wid * DOUT + c) = ov;
        }
    }
}

extern "C" void kernel_launch(void* const* d_in, const int* in_sizes, int n_in,
                              void* d_out, int out_size, void* d_ws, size_t ws_size,
                              hipStream_t stream) {
    const float* x  = (const float*)d_in[0];
    const int*   ei = (const int*)d_in[1];
    const float* W1 = (const float*)d_in[2];
    const float* b1 = (const float*)d_in[3];
    const float* W2 = (const float*)d_in[4];
    const float* b2 = (const float*)d_in[5];
    const float* W3 = (const float*)d_in[6];
    const float* b3 = (const float*)d_in[7];
    float* out = (float*)d_out;

    const int N = in_sizes[0] / DIN;  // 50000
    const int E = in_sizes[1] / 2;    // 600000
    const int* row = ei;
    const int* col = ei + E;

    // workspace layout:
    // dinv[Na] | cnt[Na] | off[Na] | bsum[256] | posw[Ea] | epack[Ea] int2 |
    // y[N*ZS] bf16 | z1[N*ZS] bf16 | s1[Na] | s2[Na] | M2[128*40] | c1[64] | c2[64] | WT[64*512]
    const int Na = (N + 255) & ~255;
    const int Ea = (E + 255) & ~255;
    float* dinv   = (float*)d_ws;
    int*   cnt    = (int*)(dinv + Na);
    int*   off    = cnt + Na;
    int*   bsum   = off + Na;
    int*   posw   = bsum + 256;
    int2*  epack  = (int2*)(posw + Ea);
    __hip_bfloat16* y  = (__hip_bfloat16*)(epack + Ea);
    __hip_bfloat16* z1 = y + (long)N * ZS;
    float* s1 = (float*)(z1 + (long)N * ZS);
    float* s2 = s1 + Na;
    float* M2 = s2 + Na;
    float* c1 = M2 + 128 * 40;
    float* c2 = c1 + 64;
    __hip_bfloat16* WT = (__hip_bfloat16*)(c2 + 64);

    const int B = 256;
    const int nb = (N + 1023) / 1024;  // 49
    int gemm_grid = (N + 31) / 32;     // 1563
    int cblocks   = (E + B - 1) / B;   // 2344
    int scat_grid = cblocks;
    int node_wave_blocks = (int)(((long)N * 64 + B - 1) / B);  // 12500

    // K1: zero cnt, M2 = W2 @ W3
    k_init<<<(Na + B - 1) / B, B, 0, stream>>>(cnt, Na, W2, W3, M2);
    // K2: fused count+rank || WT || cvec
    k_count<<<cblocks + 128 + 1, B, 0, stream>>>(col, cnt, posw, E,
                                                 W1, M2, b1, b2, W3, WT, c1, c2, cblocks);
    // K3: dinv + chunk scan + off[N]=E
    k_prep<<<256, B, 0, stream>>>(cnt, dinv, off, bsum, N, E, nb);
    // K4: chunk-prefix add
    k_scan_add<<<nb - 1, B, 0, stream>>>(off, bsum, N, nb);
    // K5: fused gemm || atomic-free scatter (nt epack store)
    k_gemm_scatter<<<gemm_grid + scat_grid, B, 0, stream>>>(
        x, WT, y, N, row, col, dinv, off, posw, epack, E, gemm_grid);
    // K6-8: three Ahat propagations (s embedded in cols 40-41 of z rows)
    prop64_kernel<0><<<node_wave_blocks, B, 0, stream>>>(
        y, dinv, off, epack, s1, nullptr, nullptr, nullptr, nullptr, nullptr,
        z1, nullptr, N);
    prop64_kernel<1><<<node_wave_blocks, B, 0, stream>>>(
        z1, dinv, off, epack, s2, nullptr, nullptr, nullptr, nullptr, nullptr,
        y, nullptr, N);
    prop64_kernel<2><<<node_wave_blocks, B, 0, stream>>>(
        y, dinv, off, epack, nullptr, s1, s2, c1, c2, b3,
        nullptr, out, N);
}